// Round 13
// baseline (199.914 us; speedup 1.0000x reference)
//
#include <hip/hip_runtime.h>
#include <math.h>

// Problem constants
#define BQ 8
#define SEQ 577
#define CH 768
#define NH 12
#define HD 64
#define M_ROWS (BQ * SEQ)      // 4616
#define QKV_CH (3 * CH)        // 2304
#define NX (M_ROWS * CH)       // 3545088
#define EPSF 1.1920929e-07f
#define F2P31 2147483648.0f    // float32(2^31 - 1) rounds to 2^31 -- replicate jnp

#define VT_ROW 640             // Vt row bytes (577 padded, 64B-aligned rows)
#define P_STRIDE 688           // P LDS row stride bytes (16B multiple for ds_read_b128)

// 64 atomic slots, each padded to 64B (16 u32) to avoid same-line serialization.
#define NSLOT 64
#define SLOT_STRIDE 16

typedef __attribute__((ext_vector_type(4))) int i32x4;

// max over the 64 padded slots -> scale. Bit-exact: max of partial maxes.
__device__ __forceinline__ float slot_scale(const unsigned* __restrict__ s) {
  float m = 0.f;
#pragma unroll
  for (int i = 0; i < NSLOT; ++i) m = fmaxf(m, __uint_as_float(s[i * SLOT_STRIDE]));
  return fmaxf(m / 127.0f, EPSF);
}

// ---------------- fused prep: blocks [0,3072) weight-quant rows; [3072,4096) absmax(x) ----
__global__ __launch_bounds__(256) void k_prep(
    const float* __restrict__ x, const float* __restrict__ w_qkv,
    const float* __restrict__ w_proj,
    signed char* __restrict__ WQ8, float* __restrict__ SWQ,
    signed char* __restrict__ WP8, float* __restrict__ SWP,
    unsigned* __restrict__ mxx) {
  __shared__ float red[4];
  int blk = blockIdx.x, tid = threadIdx.x;
  if (blk < QKV_CH + CH) {
    const float* wr; signed char* w8; float* sw; int r;
    if (blk < QKV_CH) { r = blk; wr = w_qkv + (size_t)r * CH; w8 = WQ8 + (size_t)r * CH; sw = SWQ; }
    else { r = blk - QKV_CH; wr = w_proj + (size_t)r * CH; w8 = WP8 + (size_t)r * CH; sw = SWP; }
    const float4* wr4 = (const float4*)wr;
    float4 v = {0.f, 0.f, 0.f, 0.f};
    float m = 0.f;
    if (tid < CH / 4) {
      v = wr4[tid];
      m = fmaxf(fmaxf(fabsf(v.x), fabsf(v.y)), fmaxf(fabsf(v.z), fabsf(v.w)));
    }
#pragma unroll
    for (int o = 32; o; o >>= 1) m = fmaxf(m, __shfl_xor(m, o, 64));
    if ((tid & 63) == 0) red[tid >> 6] = m;
    __syncthreads();
    float mm = fmaxf(fmaxf(red[0], red[1]), fmaxf(red[2], red[3]));
    float s = fmaxf(mm / 127.0f, EPSF);
    if (tid == 0) sw[r] = s;
    if (tid < CH / 4) {
      int pk = 0;
#pragma unroll
      for (int u = 0; u < 4; ++u) {
        float xv = (u == 0) ? v.x : (u == 1) ? v.y : (u == 2) ? v.z : v.w;
        float q = rintf(xv / s);
        q = fminf(fmaxf(q, -128.f), 127.f);
        pk |= ((int)(signed char)q & 0xff) << (u * 8);
      }
      ((int*)w8)[tid] = pk;
    }
  } else {
    int ab = blk - (QKV_CH + CH);            // [0,1024)
    const float4* x4 = (const float4*)x;
    float m = 0.f;
    for (int i = ab * 256 + tid; i < NX / 4; i += 1024 * 256) {
      float4 v = x4[i];
      m = fmaxf(m, fmaxf(fmaxf(fabsf(v.x), fabsf(v.y)), fmaxf(fabsf(v.z), fabsf(v.w))));
    }
#pragma unroll
    for (int o = 32; o; o >>= 1) m = fmaxf(m, __shfl_xor(m, o, 64));
    if ((tid & 63) == 0) red[tid >> 6] = m;
    __syncthreads();
    if (tid == 0)
      atomicMax(&mxx[(ab & (NSLOT - 1)) * SLOT_STRIDE],
                __float_as_uint(fmaxf(fmaxf(red[0], red[1]), fmaxf(red[2], red[3]))));
  }
}

// ---------------- per-tensor activation quant (float4 loads, packed int8x4 store) ----------
__global__ void k_aquant(const float* __restrict__ x, int n,
                         const unsigned* __restrict__ mxx, signed char* __restrict__ x8) {
  float s = slot_scale(mxx);
  int n4 = n >> 2;
  const float4* x4 = (const float4*)x;
  int* dst = (int*)x8;
  int stride = gridDim.x * blockDim.x;
  for (int i = blockIdx.x * blockDim.x + threadIdx.x; i < n4; i += stride) {
    float4 v = x4[i];
    int pk = 0;
#pragma unroll
    for (int u = 0; u < 4; ++u) {
      float xv = (u == 0) ? v.x : (u == 1) ? v.y : (u == 2) ? v.z : v.w;
      float q = rintf(xv / s);                 // keep correctly-rounded fdiv (ref semantics)
      q = fminf(fmaxf(q, -128.f), 127.f);
      pk |= ((int)(signed char)q & 0xff) << (u * 8);
    }
    dst[i] = pk;
  }
}

// ---- GEMM1 (MFMA): 128x64 tiles -> grid 36x37=1332 blocks (proven split pattern).
// Wave w: row-half (w&1), col-half (w>>1) of 32 cols; acc[4][2].
__global__ __launch_bounds__(256) void k_gemm_qkv(
    const signed char* __restrict__ A, const signed char* __restrict__ Bm,
    const float* __restrict__ swq, const float* __restrict__ bias,
    const unsigned* __restrict__ mxx, int* __restrict__ Cq, unsigned* __restrict__ mxq) {
  __shared__ __align__(16) signed char As[8192], Bs[4096];
  __shared__ float red[4];
  int t = threadIdx.x;
  int lane = t & 63, w = t >> 6;
  int c = lane & 15, q = lane >> 4;
  int lr = lane >> 2;
  int ksb = (lane & 3) << 4;
  int arow0 = blockIdx.y * 128, bcol0 = blockIdx.x * 64;
  int arow = arow0 + (w & 1) * 64;
  int bcol = bcol0 + (w >> 1) * 32;
  const signed char* Aw = As + ((w & 1) << 12);
  const signed char* Bw = Bs + ((w >> 1) << 11);   // 32-row half (2KB)
  i32x4 acc[4][2] = {};
  for (int k0 = 0; k0 < CH; k0 += 64) {
#pragma unroll
    for (int u = 0; u < 2; ++u) {
      int row = (w << 5) + (u << 4) + lr;
      __builtin_amdgcn_global_load_lds(
          (const __attribute__((address_space(1))) void*)(A + (size_t)(arow0 + row) * CH + k0 + ksb),
          (__attribute__((address_space(3))) void*)(As + (w << 11) + (u << 10)),
          16, 0, 0);
    }
    {
      int row = (w << 4) + lr;               // 64 B-rows across 4 waves
      __builtin_amdgcn_global_load_lds(
          (const __attribute__((address_space(1))) void*)(Bm + (size_t)(bcol0 + row) * CH + k0 + ksb),
          (__attribute__((address_space(3))) void*)(Bs + (w << 10)),
          16, 0, 0);
    }
    __syncthreads();
    i32x4 af[4], bf[2];
#pragma unroll
    for (int i = 0; i < 4; ++i)
      af[i] = *(const i32x4*)(Aw + (((i << 4) + c) << 6) + (q << 4));
#pragma unroll
    for (int j = 0; j < 2; ++j)
      bf[j] = *(const i32x4*)(Bw + (((j << 4) + c) << 6) + (q << 4));
#pragma unroll
    for (int i = 0; i < 4; ++i)
#pragma unroll
      for (int j = 0; j < 2; ++j)
        acc[i][j] = __builtin_amdgcn_mfma_i32_16x16x64_i8(af[i], bf[j], acc[i][j], 0, 0, 0);
    __syncthreads();
  }
  float s_x = slot_scale(mxx);
  float lmax = 0.f;
#pragma unroll
  for (int j = 0; j < 2; ++j) {
    int ccol = bcol + j * 16 + c;
    float accs = s_x * swq[ccol];
    int bint = (int)rintf(bias[ccol] / accs);
#pragma unroll
    for (int i = 0; i < 4; ++i)
#pragma unroll
      for (int r = 0; r < 4; ++r) {
        int rr = arow + i * 16 + q * 4 + r;
        if (rr < M_ROWS) {
          int qv = acc[i][j][r] + bint;
          Cq[(size_t)rr * QKV_CH + ccol] = qv;
          lmax = fmaxf(lmax, fabsf((float)qv * accs));
        }
      }
  }
#pragma unroll
  for (int off = 32; off; off >>= 1) lmax = fmaxf(lmax, __shfl_xor(lmax, off, 64));
  if (lane == 0) red[w] = lmax;
  __syncthreads();
  if (t == 0)
    atomicMax(&mxq[((blockIdx.y * 36 + blockIdx.x) & (NSLOT - 1)) * SLOT_STRIDE],
              __float_as_uint(fmaxf(fmaxf(red[0], red[1]), fmaxf(red[2], red[3]))));
}

// ---- requant: blocks [0,870) Q/K col-fixed threads; [870,1830) V LDS-transpose tiles ----
#define QK_BLKS 870   // 6 col-chunks x 145 row-chunks
__global__ __launch_bounds__(256) void k_qkv_requant(
    const int* __restrict__ Cq, const float* __restrict__ swq,
    const unsigned* __restrict__ mxx, const unsigned* __restrict__ mxq,
    signed char* __restrict__ Q8, signed char* __restrict__ K8,
    signed char* __restrict__ VT8) {
  float s_x = slot_scale(mxx);
  float s_qkv = slot_scale(mxq);
  int blk = blockIdx.x, tid = threadIdx.x;
  if (blk < QK_BLKS) {
    int bx = blk % 6, by = blk / 6;
    int o = bx * 256 + tid;                  // fixed channel per thread, [0,1536)
    float accs = s_x * swq[o];
    float ns = accs / s_qkv;
    int e; float f = frexpf(ns, &e);
    float mm = floorf(f * F2P31 + 0.5f);     // hoisted: once per thread
    float pw = __int_as_float((e + 96) << 23);  // 2^(e-31) exact
    int isK = (o >= CH);
    int rem = o - (isK ? CH : 0);
    int h = rem >> 6, d = rem & 63;
    signed char* dstb = isK ? K8 : Q8;
    int bn0 = by * 32;
    int bnend = min(bn0 + 32, M_ROWS);
    for (int bn = bn0; bn < bnend; ++bn) {
      int qv = Cq[(size_t)bn * QKV_CH + o];  // wave reads 256B contiguous
      float qf = (float)qv * accs;
      float z = rintf(qf / accs);
      float t8 = rintf((z * mm) * pw);
      t8 = fminf(fmaxf(t8, -128.f), 127.f);
      int b = bn / SEQ, n = bn - b * SEQ;
      dstb[(((size_t)(b * NH + h) * SEQ + n) << 6) + d] = (signed char)t8;
    }
  } else {
    // V: one (bh, 64-n) tile per block, transpose through LDS -> coalesced VT8 writes
    __shared__ __align__(16) signed char VTt[64 * 68];
    int vt = blk - QK_BLKS;                  // [0, 960)
    int bh = vt / 10, n0 = (vt - bh * 10) * 64;
    int b = bh / NH, h = bh - b * NH;
    int od = tid & 63;                       // d within head
    int o = 2 * CH + h * 64 + od;
    float accs = s_x * swq[o];
    float ns = accs / s_qkv;
    int e; float f = frexpf(ns, &e);
    float mm = floorf(f * F2P31 + 0.5f);
    float pw = __int_as_float((e + 96) << 23);
    int nr = tid >> 6;                       // 0..3
    for (int p = 0; p < 16; ++p) {
      int nl = nr * 16 + p;
      int n = n0 + nl;
      signed char v = 0;
      if (n < SEQ) {
        int qv = Cq[(size_t)(b * SEQ + n) * QKV_CH + o];
        float qf = (float)qv * accs;
        float z = rintf(qf / accs);
        float t8 = rintf((z * mm) * pw);
        t8 = fminf(fmaxf(t8, -128.f), 127.f);
        v = (signed char)t8;
      }
      VTt[od * 68 + nl] = v;
    }
    __syncthreads();
    int w16 = tid & 15, dr = tid >> 4;
#pragma unroll
    for (int pp = 0; pp < 4; ++pp) {
      int d = pp * 16 + dr;
      int val = *(const int*)&VTt[d * 68 + w16 * 4];
      *(int*)(VT8 + (size_t)bh * (64 * VT_ROW) + (size_t)d * VT_ROW + n0 + w16 * 4) = val;
    }
  }
}

// ---- attention: 1-D grid 3552, XCD-pinned; integer shiftmax; 16x16x64 MFMA;
// (256,4): proven fit -- waves/EU x VGPR <= 256, sv[10] needs ~64 VGPR. Do not raise.
__global__ __launch_bounds__(256, 4) void k_attn(
    const signed char* __restrict__ Q8, const signed char* __restrict__ K8,
    const signed char* __restrict__ VT8, const unsigned* __restrict__ mxq,
    int* __restrict__ ctxi, unsigned* __restrict__ mxc) {
  __shared__ __align__(16) unsigned char P[16 * P_STRIDE];   // probs [row][m]
  __shared__ int Rmax[4][16];
  __shared__ unsigned long long Rsum[4][16];
  __shared__ float Rav[4];
  int tid = threadIdx.x;
  int t = tid & 63, wid = tid >> 6;
  int lin = blockIdx.x;
  int j = lin >> 3;
  int bh = (lin & 7) * 12 + j / 37;   // 8 XCDs x 12 bh each
  int qt = j % 37;
  int b = bh / NH, h = bh - b * NH;
  int col = t & 15, q4 = t >> 4;
  const signed char* Qb = Q8 + (((size_t)bh * SEQ + qt * 16 + col) << 6);
  i32x4 qa = *(const i32x4*)(Qb + q4 * 16);
  const signed char* Kb = K8 + ((size_t)bh * SEQ << 6);
  int kt0 = wid * 10;
  i32x4 sv[10];
  bool vld[10];
  int mx[4] = {-2147483647 - 1, -2147483647 - 1, -2147483647 - 1, -2147483647 - 1};
#pragma unroll
  for (int u = 0; u < 10; ++u) {
    int kt = kt0 + u;
    int krow = min(kt * 16 + col, SEQ - 1);          // clamp: dead tiles read in-bounds
    const signed char* kr = Kb + ((size_t)krow << 6);
    i32x4 kb = *(const i32x4*)(kr + q4 * 16);
    i32x4 a = {0, 0, 0, 0};
    a = __builtin_amdgcn_mfma_i32_16x16x64_i8(qa, kb, a, 0, 0, 0);
    sv[u] = a;
    bool valid = (kt < 36) | ((kt == 36) & (col < 1));
    vld[u] = valid;
#pragma unroll
    for (int r = 0; r < 4; ++r)
      if (valid) mx[r] = max(mx[r], a[r]);
  }
#pragma unroll
  for (int r = 0; r < 4; ++r) {
    mx[r] = max(mx[r], __shfl_xor(mx[r], 1, 64));
    mx[r] = max(mx[r], __shfl_xor(mx[r], 2, 64));
    mx[r] = max(mx[r], __shfl_xor(mx[r], 4, 64));
    mx[r] = max(mx[r], __shfl_xor(mx[r], 8, 64));
  }
  if (col == 0) {
#pragma unroll
    for (int r = 0; r < 4; ++r) Rmax[wid][q4 * 4 + r] = mx[r];
  }
  __syncthreads();
#pragma unroll
  for (int r = 0; r < 4; ++r) {
    int row = q4 * 4 + r;
    mx[r] = max(max(Rmax[0][row], Rmax[1][row]), max(Rmax[2][row], Rmax[3][row]));
  }
  // ---- integer shiftmax constants (uniform) ----
  float s_qkv = slot_scale(mxq);
  float s_attn = (s_qkv * s_qkv) * 0.125f;
  float x0f = floorf(-1.0f / s_attn);      // identical to ref's x0 (f32 div + floor)
  int x0i = (int)x0f;
  int bi = -x0i;                           // b >= 1, < 16384 in regime
  int nx0i = 15 * x0i;
  int twob = bi << 1;
  unsigned Mq = 0xFFFFFFFFu / (unsigned)bi + 1u;   // ceil(2^32/b) mod 2^32 (0 iff b==1)
  bool bOne = (Mq == 0u);
  unsigned long long su[4] = {0ull, 0ull, 0ull, 0ull};
#pragma unroll
  for (int u = 0; u < 10; ++u) {
#pragma unroll
    for (int r = 0; r < 4; ++r) {
      int d = sv[u][r] - mx[r];                       // <=0 on valid lanes
      int xi = d + (d >> 1) - (d >> 4);               // == d + floor(d/2) - floor(d/16)
      xi = max(xi, nx0i);
      xi = min(xi, 0);                                // guards garbage (invalid lanes only)
      unsigned a = (unsigned)(-xi);                   // in [0, 15b]
      unsigned q = bOne ? a : __umulhi(a, Mq);        // exact floor(a/b) for b<16384
      int rr = (int)(a - q * (unsigned)bi);           // in [0, b)
      unsigned m = (unsigned)(twob - rr);             // m in (b, 2b], m < 2^15
      unsigned ue = (m << 15) >> (q + 1);             // == m<<(14-q) (q<15) / m>>1 (q==15)
      ue = vld[u] ? ue : 0u;
      su[r] += ue;
      sv[u][r] = (int)ue;
    }
  }
#pragma unroll
  for (int r = 0; r < 4; ++r) {
    su[r] += __shfl_xor(su[r], 1, 64);
    su[r] += __shfl_xor(su[r], 2, 64);
    su[r] += __shfl_xor(su[r], 4, 64);
    su[r] += __shfl_xor(su[r], 8, 64);
  }
  if (col == 0) {
#pragma unroll
    for (int r = 0; r < 4; ++r) Rsum[wid][q4 * 4 + r] = su[r];
  }
  __syncthreads();
  float facS[4];
#pragma unroll
  for (int r = 0; r < 4; ++r) {
    int row = q4 * 4 + r;
    unsigned long long dv = ((Rsum[0][row] + Rsum[1][row]) + Rsum[2][row]) + Rsum[3][row];
    float esum = fminf((float)dv, F2P31);   // exact-sum -> f32 RN
    // fac * 2^-24 folded once: exact pow2 scale commutes with f32 rounding of e*fac.
    facS[r] = floorf(F2P31 / esum) * 5.9604644775390625e-08f;
  }
#pragma unroll
  for (int u = 0; u < 10; ++u) {
    int kt = kt0 + u;
#pragma unroll
    for (int r = 0; r < 4; ++r) {
      float e = (float)(unsigned)sv[u][r];     // exact for e < 2^24 (realistic regime)
      int p = (int)floorf(e * facS[r]);        // == floor((e*fac)/2^24), bit-exact
      P[(q4 * 4 + r) * P_STRIDE + kt * 16 + col] = (unsigned char)p;  // covers cols 0..639
    }
  }
  __syncthreads();
  const signed char* Vb = VT8 + (size_t)bh * (64 * VT_ROW);
  i32x4 ac0 = {0, 0, 0, 0}, ac1 = {0, 0, 0, 0};
#pragma unroll
  for (int mc = 0; mc < 10; mc += 2) {
    i32x4 pa0 = *(const i32x4*)&P[col * P_STRIDE + mc * 64 + q4 * 16];
    i32x4 vb0 = *(const i32x4*)(Vb + (size_t)(wid * 16 + col) * VT_ROW + mc * 64 + q4 * 16);
    ac0 = __builtin_amdgcn_mfma_i32_16x16x64_i8(pa0, vb0, ac0, 0, 0, 0);
    i32x4 pa1 = *(const i32x4*)&P[col * P_STRIDE + (mc + 1) * 64 + q4 * 16];
    i32x4 vb1 = *(const i32x4*)(Vb + (size_t)(wid * 16 + col) * VT_ROW + (mc + 1) * 64 + q4 * 16);
    ac1 = __builtin_amdgcn_mfma_i32_16x16x64_i8(pa1, vb1, ac1, 0, 0, 0);
  }
  float pre_s = 0.0078125f * s_qkv;
  float avmax = 0.f;
#pragma unroll
  for (int r = 0; r < 4; ++r) {
    int n = qt * 16 + q4 * 4 + r;
    if (n < SEQ) {
      int cacc = ac0[r] + ac1[r];              // exact integer sum, order-free
      ctxi[((size_t)(b * SEQ + n)) * CH + h * 64 + wid * 16 + col] = cacc;
      avmax = fmaxf(avmax, fabsf((float)cacc * pre_s));
    }
  }
#pragma unroll
  for (int off = 32; off; off >>= 1) avmax = fmaxf(avmax, __shfl_xor(avmax, off, 64));
  if (t == 0) Rav[wid] = avmax;
  __syncthreads();
  if (tid == 0)
    atomicMax(&mxc[(blockIdx.x & (NSLOT - 1)) * SLOT_STRIDE],
              __float_as_uint(fmaxf(fmaxf(Rav[0], Rav[1]), fmaxf(Rav[2], Rav[3]))));
}

// ---------------- requant ctx -> int8 (vectorized x4) ----------------
__global__ void k_ctx_requant(const int* __restrict__ ctxi, const unsigned* __restrict__ mxq,
                              const unsigned* __restrict__ mxc, signed char* __restrict__ C8) {
  float s_qkv = slot_scale(mxq);
  float pre_s = 0.0078125f * s_qkv;
  float s_ctx = slot_scale(mxc);
  float ns = pre_s / s_ctx;
  int e;
  float f = frexpf(ns, &e);
  float mm = floorf(f * F2P31 + 0.5f);
  float pw = exp2f((float)e - 31.0f);
  int total4 = (M_ROWS * CH) / 4;
  int stride = gridDim.x * blockDim.x;
  const int4* src = (const int4*)ctxi;
  int* dst = (int*)C8;
  for (int i = blockIdx.x * blockDim.x + threadIdx.x; i < total4; i += stride) {
    int4 v = src[i];
    int pk = 0;
#pragma unroll
    for (int u = 0; u < 4; ++u) {
      int cv = (u == 0) ? v.x : (u == 1) ? v.y : (u == 2) ? v.z : v.w;
      float cf = (float)cv * pre_s;
      float z = rintf(cf / pre_s);
      float t8 = rintf((z * mm) * pw);
      t8 = fminf(fmaxf(t8, -128.f), 127.f);
      pk |= ((int)(signed char)t8 & 0xff) << (u * 8);
    }
    dst[i] = pk;
  }
}

// ---- GEMM2 (MFMA): 128x64 tiles -> grid 12x37=444 blocks (proven round-12 winner).
__global__ __launch_bounds__(256) void k_gemm_out(
    const signed char* __restrict__ A, const signed char* __restrict__ Bm,
    const float* __restrict__ swp, const float* __restrict__ bias,
    const unsigned* __restrict__ mxc, float* __restrict__ outp) {
  __shared__ __align__(16) signed char As[8192], Bs[4096];
  int t = threadIdx.x;
  int lane = t & 63, w = t >> 6;
  int c = lane & 15, q = lane >> 4;
  int lr = lane >> 2;
  int ksb = (lane & 3) << 4;
  int arow0 = blockIdx.y * 128, bcol0 = blockIdx.x * 64;
  int arow = arow0 + (w & 1) * 64;
  int bcol = bcol0 + (w >> 1) * 32;
  const signed char* Aw = As + ((w & 1) << 12);
  const signed char* Bw = Bs + ((w >> 1) << 11);   // 32-row half (2KB)
  i32x4 acc[4][2] = {};
  for (int k0 = 0; k0 < CH; k0 += 64) {
#pragma unroll
    for (int u = 0; u < 2; ++u) {
      int row = (w << 5) + (u << 4) + lr;
      __builtin_amdgcn_global_load_lds(
          (const __attribute__((address_space(1))) void*)(A + (size_t)(arow0 + row) * CH + k0 + ksb),
          (__attribute__((address_space(3))) void*)(As + (w << 11) + (u << 10)),
          16, 0, 0);
    }
    {
      int row = (w << 4) + lr;               // 64 B-rows across 4 waves
      __builtin_amdgcn_global_load_lds(
          (const __attribute__((address_space(1))) void*)(Bm + (size_t)(bcol0 + row) * CH + k0 + ksb),
          (__attribute__((address_space(3))) void*)(Bs + (w << 10)),
          16, 0, 0);
    }
    __syncthreads();
    i32x4 af[4], bf[2];
#pragma unroll
    for (int i = 0; i < 4; ++i)
      af[i] = *(const i32x4*)(Aw + (((i << 4) + c) << 6) + (q << 4));
#pragma unroll
    for (int j = 0; j < 2; ++j)
      bf[j] = *(const i32x4*)(Bw + (((j << 4) + c) << 6) + (q << 4));
#pragma unroll
    for (int i = 0; i < 4; ++i)
#pragma unroll
      for (int j = 0; j < 2; ++j)
        acc[i][j] = __builtin_amdgcn_mfma_i32_16x16x64_i8(af[i], bf[j], acc[i][j], 0, 0, 0);
    __syncthreads();
  }
  float s_ctx = slot_scale(mxc);
#pragma unroll
  for (int j = 0; j < 2; ++j) {
    int ccol = bcol + j * 16 + c;
    float outs = s_ctx * swp[ccol];
    int bint = (int)rintf(bias[ccol] / outs);
#pragma unroll
    for (int i = 0; i < 4; ++i)
#pragma unroll
      for (int r = 0; r < 4; ++r) {
        int rr = arow + i * 16 + q * 4 + r;
        if (rr < M_ROWS)
          outp[(size_t)rr * CH + ccol] = (float)(acc[i][j][r] + bint) * outs;
      }
  }
}

extern "C" void kernel_launch(void* const* d_in, const int* in_sizes, int n_in,
                              void* d_out, int out_size, void* d_ws, size_t ws_size,
                              hipStream_t stream) {
  const float* x = (const float*)d_in[0];
  const float* w_qkv = (const float*)d_in[1];
  const float* b_qkv = (const float*)d_in[2];
  const float* w_proj = (const float*)d_in[3];
  const float* b_proj = (const float*)d_in[4];
  float* outp = (float*)d_out;

  // ---- workspace: bump allocator, 4 KB aligned ----
  char* ws = (char*)d_ws;
  size_t off = 0;
  auto alloc = [&](size_t sz) -> char* {
    char* p = ws + off;
    off = (off + sz + 4095) & ~(size_t)4095;
    return p;
  };
  // 3 slot arrays of 64 x 64B: [0]=max|x| [1]=max|qkv_f| [2]=max|ctx_f|
  unsigned* mxx = (unsigned*)alloc(3 * NSLOT * SLOT_STRIDE * 4);
  unsigned* mxq = mxx + NSLOT * SLOT_STRIDE;
  unsigned* mxc = mxq + NSLOT * SLOT_STRIDE;
  float* SWQ = (float*)alloc(QKV_CH * 4);
  float* SWP = (float*)alloc(CH * 4);
  signed char* WQ8 = (signed char*)alloc((size_t)QKV_CH * CH);
  signed char* WP8 = (signed char*)alloc((size_t)CH * CH);
  signed char* X8  = (signed char*)alloc((size_t)(M_ROWS + 128) * CH);
  signed char* Q8  = (signed char*)alloc((size_t)M_ROWS * CH);
  signed char* K8  = (signed char*)alloc((size_t)M_ROWS * CH);
  signed char* VT8 = (signed char*)alloc((size_t)BQ * NH * 64 * VT_ROW);
  signed char* C8  = (signed char*)alloc((size_t)(M_ROWS + 128) * CH);
  int* QKVI = (int*)alloc((size_t)M_ROWS * QKV_CH * 4);
  int* CTXI = (int*)alloc((size_t)M_ROWS * CH * 4);
  (void)ws_size;

  hipMemsetAsync(mxx, 0, 3 * NSLOT * SLOT_STRIDE * 4, stream);
  // 1: fused weight quant + absmax(x)
  k_prep<<<QKV_CH + CH + 1024, 256, 0, stream>>>(x, w_qkv, w_proj, WQ8, SWQ, WP8, SWP, mxx);
  // 2: activation quant
  k_aquant<<<2048, 256, 0, stream>>>(x, NX, mxx, X8);
  // 3: qkv GEMM (128x64 tiles, 1332 blocks)
  dim3 g1(QKV_CH / 64, (M_ROWS + 127) / 128);
  k_gemm_qkv<<<g1, 256, 0, stream>>>(X8, WQ8, SWQ, b_qkv, mxx, QKVI, mxq);
  // 4: requant (Q/K col-fixed + V LDS-transpose)
  k_qkv_requant<<<QK_BLKS + BQ * NH * 10, 256, 0, stream>>>(QKVI, SWQ, mxx, mxq, Q8, K8, VT8);
  // 5: attention (XCD-pinned 1-D grid, integer shiftmax, 4 blocks/CU proven)
  k_attn<<<37 * BQ * NH, 256, 0, stream>>>(Q8, K8, VT8, mxq, CTXI, mxc);
  // 6: ctx requant
  k_ctx_requant<<<1024, 256, 0, stream>>>(CTXI, mxq, mxc, C8);
  // 7: output GEMM (128x64 tiles, 444 blocks)
  dim3 g2(CH / 64, (M_ROWS + 127) / 128);
  k_gemm_out<<<g2, 256, 0, stream>>>(C8, WP8, SWP, b_proj, mxc, outp);
}

// Round 14
// 190.711 us; speedup vs baseline: 1.0483x; 1.0483x over previous
//
#include <hip/hip_runtime.h>
#include <math.h>

// Problem constants
#define BQ 8
#define SEQ 577
#define CH 768
#define NH 12
#define HD 64
#define M_ROWS (BQ * SEQ)      // 4616
#define QKV_CH (3 * CH)        // 2304
#define NX (M_ROWS * CH)       // 3545088
#define EPSF 1.1920929e-07f
#define F2P31 2147483648.0f    // float32(2^31 - 1) rounds to 2^31 -- replicate jnp

#define VT_ROW 640             // Vt row bytes (577 padded, 64B-aligned rows)
#define P_STRIDE 688           // P LDS row stride bytes (16B multiple for ds_read_b128)

// 64 atomic slots, each padded to 64B (16 u32) to avoid same-line serialization.
#define NSLOT 64
#define SLOT_STRIDE 16

typedef __attribute__((ext_vector_type(4))) int i32x4;

// Bijective XCD-aware remap (m204 variant): blocks grouped into contiguous chunks per XCD.
// Pure index permutation -> correctness-neutral, L2-locality heuristic.
__device__ __forceinline__ int xcd_swizzle(int bid, int nwg) {
  int q = nwg >> 3, r = nwg & 7;
  int xcd = bid & 7, idx = bid >> 3;
  int base = (xcd < r) ? xcd * (q + 1) : r * (q + 1) + (xcd - r) * q;
  int sz = (xcd < r) ? q + 1 : q;
  return (idx < sz) ? base + idx : bid;   // tail ids (idx>=sz) keep identity (still bijective
                                          // since those bids only occur when idx<sz fails)
}

// max over the 64 padded slots -> scale. Bit-exact: max of partial maxes.
__device__ __forceinline__ float slot_scale(const unsigned* __restrict__ s) {
  float m = 0.f;
#pragma unroll
  for (int i = 0; i < NSLOT; ++i) m = fmaxf(m, __uint_as_float(s[i * SLOT_STRIDE]));
  return fmaxf(m / 127.0f, EPSF);
}

// ---- shared MFMA core, m97 structure: 128x128 block tile, BK=64 bytes,
// global_load_lds(16B) staging into linear LDS, ds_read_b128 fragments,
// one 16x16x64 i8 MFMA per fragment pair.
__device__ __forceinline__ void mfma_gemm_core_lds(
    const signed char* __restrict__ A, const signed char* __restrict__ Bm,
    signed char* As, signed char* Bs,
    int arow0, int bcol0, int w, int lane, i32x4 acc[4][4]) {
  int c = lane & 15, q = lane >> 4;
  int lr = lane >> 2;            // 0..15 : row within 16-row stage group
  int ksb = (lane & 3) << 4;     // 0,16,32,48 : byte col within 64B row
  const signed char* Aw = As + ((w & 1) << 12);   // (w&1)*64 rows * 64B
  const signed char* Bw = Bs + ((w >> 1) << 12);  // (w>>1)*64 rows * 64B
  for (int k0 = 0; k0 < CH; k0 += 64) {
#pragma unroll
    for (int u = 0; u < 2; ++u) {
      int row = (w << 5) + (u << 4) + lr;
      __builtin_amdgcn_global_load_lds(
          (const __attribute__((address_space(1))) void*)(A + (size_t)(arow0 + row) * CH + k0 + ksb),
          (__attribute__((address_space(3))) void*)(As + (w << 11) + (u << 10)),
          16, 0, 0);
      __builtin_amdgcn_global_load_lds(
          (const __attribute__((address_space(1))) void*)(Bm + (size_t)(bcol0 + row) * CH + k0 + ksb),
          (__attribute__((address_space(3))) void*)(Bs + (w << 11) + (u << 10)),
          16, 0, 0);
    }
    __syncthreads();
    i32x4 af[4], bf[4];
#pragma unroll
    for (int i = 0; i < 4; ++i)
      af[i] = *(const i32x4*)(Aw + (((i << 4) + c) << 6) + (q << 4));
#pragma unroll
    for (int j = 0; j < 4; ++j)
      bf[j] = *(const i32x4*)(Bw + (((j << 4) + c) << 6) + (q << 4));
#pragma unroll
    for (int i = 0; i < 4; ++i)
#pragma unroll
      for (int j = 0; j < 4; ++j)
        acc[i][j] = __builtin_amdgcn_mfma_i32_16x16x64_i8(af[i], bf[j], acc[i][j], 0, 0, 0);
    __syncthreads();
  }
}

// ---------------- fused prep: blocks [0,3072) weight-quant rows; [3072,4096) absmax(x) ----
__global__ __launch_bounds__(256) void k_prep(
    const float* __restrict__ x, const float* __restrict__ w_qkv,
    const float* __restrict__ w_proj,
    signed char* __restrict__ WQ8, float* __restrict__ SWQ,
    signed char* __restrict__ WP8, float* __restrict__ SWP,
    unsigned* __restrict__ mxx) {
  __shared__ float red[4];
  int blk = blockIdx.x, tid = threadIdx.x;
  if (blk < QKV_CH + CH) {
    const float* wr; signed char* w8; float* sw; int r;
    if (blk < QKV_CH) { r = blk; wr = w_qkv + (size_t)r * CH; w8 = WQ8 + (size_t)r * CH; sw = SWQ; }
    else { r = blk - QKV_CH; wr = w_proj + (size_t)r * CH; w8 = WP8 + (size_t)r * CH; sw = SWP; }
    const float4* wr4 = (const float4*)wr;
    float4 v = {0.f, 0.f, 0.f, 0.f};
    float m = 0.f;
    if (tid < CH / 4) {
      v = wr4[tid];
      m = fmaxf(fmaxf(fabsf(v.x), fabsf(v.y)), fmaxf(fabsf(v.z), fabsf(v.w)));
    }
#pragma unroll
    for (int o = 32; o; o >>= 1) m = fmaxf(m, __shfl_xor(m, o, 64));
    if ((tid & 63) == 0) red[tid >> 6] = m;
    __syncthreads();
    float mm = fmaxf(fmaxf(red[0], red[1]), fmaxf(red[2], red[3]));
    float s = fmaxf(mm / 127.0f, EPSF);
    if (tid == 0) sw[r] = s;
    if (tid < CH / 4) {
      int pk = 0;
#pragma unroll
      for (int u = 0; u < 4; ++u) {
        float xv = (u == 0) ? v.x : (u == 1) ? v.y : (u == 2) ? v.z : v.w;
        float q = rintf(xv / s);
        q = fminf(fmaxf(q, -128.f), 127.f);
        pk |= ((int)(signed char)q & 0xff) << (u * 8);
      }
      ((int*)w8)[tid] = pk;
    }
  } else {
    int ab = blk - (QKV_CH + CH);            // [0,1024)
    const float4* x4 = (const float4*)x;
    float m = 0.f;
    for (int i = ab * 256 + tid; i < NX / 4; i += 1024 * 256) {
      float4 v = x4[i];
      m = fmaxf(m, fmaxf(fmaxf(fabsf(v.x), fabsf(v.y)), fmaxf(fabsf(v.z), fabsf(v.w))));
    }
#pragma unroll
    for (int o = 32; o; o >>= 1) m = fmaxf(m, __shfl_xor(m, o, 64));
    if ((tid & 63) == 0) red[tid >> 6] = m;
    __syncthreads();
    if (tid == 0)
      atomicMax(&mxx[(ab & (NSLOT - 1)) * SLOT_STRIDE],
                __float_as_uint(fmaxf(fmaxf(red[0], red[1]), fmaxf(red[2], red[3]))));
  }
}

// ---------------- per-tensor activation quant (float4 loads, packed int8x4 store) ----------
__global__ void k_aquant(const float* __restrict__ x, int n,
                         const unsigned* __restrict__ mxx, signed char* __restrict__ x8) {
  float s = slot_scale(mxx);
  int n4 = n >> 2;
  const float4* x4 = (const float4*)x;
  int* dst = (int*)x8;
  int stride = gridDim.x * blockDim.x;
  for (int i = blockIdx.x * blockDim.x + threadIdx.x; i < n4; i += stride) {
    float4 v = x4[i];
    int pk = 0;
#pragma unroll
    for (int u = 0; u < 4; ++u) {
      float xv = (u == 0) ? v.x : (u == 1) ? v.y : (u == 2) ? v.z : v.w;
      float q = rintf(xv / s);                 // keep correctly-rounded fdiv (ref semantics)
      q = fminf(fmaxf(q, -128.f), 127.f);
      pk |= ((int)(signed char)q & 0xff) << (u * 8);
    }
    dst[i] = pk;
  }
}

// ---------------- GEMM1 (MFMA): 128x128 tiles (proven best), XCD-swizzled 1-D grid ----------
#define QKV_GX 18
#define QKV_GY 37
__global__ __launch_bounds__(256) void k_gemm_qkv(
    const signed char* __restrict__ A, const signed char* __restrict__ Bm,
    const float* __restrict__ swq, const float* __restrict__ bias,
    const unsigned* __restrict__ mxx, int* __restrict__ Cq, unsigned* __restrict__ mxq) {
  __shared__ __align__(16) signed char As[8192], Bs[8192];
  __shared__ float red[4];
  int t = threadIdx.x;
  int lane = t & 63, w = t >> 6;
  int c = lane & 15, q = lane >> 4;
  int sw_id = xcd_swizzle(blockIdx.x, QKV_GX * QKV_GY);
  int bx = sw_id % QKV_GX, by = sw_id / QKV_GX;
  int arow = by * 128 + (w & 1) * 64;
  int bcol = bx * 128 + (w >> 1) * 64;
  i32x4 acc[4][4] = {};
  mfma_gemm_core_lds(A, Bm, As, Bs, by * 128, bx * 128, w, lane, acc);
  float s_x = slot_scale(mxx);
  float lmax = 0.f;
#pragma unroll
  for (int j = 0; j < 4; ++j) {
    int ccol = bcol + j * 16 + c;
    float accs = s_x * swq[ccol];
    int bint = (int)rintf(bias[ccol] / accs);
#pragma unroll
    for (int i = 0; i < 4; ++i)
#pragma unroll
      for (int r = 0; r < 4; ++r) {
        int rr = arow + i * 16 + q * 4 + r;
        if (rr < M_ROWS) {
          int qv = acc[i][j][r] + bint;
          Cq[(size_t)rr * QKV_CH + ccol] = qv;
          lmax = fmaxf(lmax, fabsf((float)qv * accs));
        }
      }
  }
#pragma unroll
  for (int off = 32; off; off >>= 1) lmax = fmaxf(lmax, __shfl_xor(lmax, off, 64));
  if (lane == 0) red[w] = lmax;
  __syncthreads();
  if (t == 0)
    atomicMax(&mxq[(blockIdx.x & (NSLOT - 1)) * SLOT_STRIDE],
              __float_as_uint(fmaxf(fmaxf(red[0], red[1]), fmaxf(red[2], red[3]))));
}

// ---- requant: blocks [0,870) Q/K col-fixed threads; [870,1830) V LDS-transpose tiles ----
#define QK_BLKS 870   // 6 col-chunks x 145 row-chunks
__global__ __launch_bounds__(256) void k_qkv_requant(
    const int* __restrict__ Cq, const float* __restrict__ swq,
    const unsigned* __restrict__ mxx, const unsigned* __restrict__ mxq,
    signed char* __restrict__ Q8, signed char* __restrict__ K8,
    signed char* __restrict__ VT8) {
  float s_x = slot_scale(mxx);
  float s_qkv = slot_scale(mxq);
  int blk = blockIdx.x, tid = threadIdx.x;
  if (blk < QK_BLKS) {
    int bx = blk % 6, by = blk / 6;
    int o = bx * 256 + tid;                  // fixed channel per thread, [0,1536)
    float accs = s_x * swq[o];
    float ns = accs / s_qkv;
    int e; float f = frexpf(ns, &e);
    float mm = floorf(f * F2P31 + 0.5f);     // hoisted: once per thread
    float pw = __int_as_float((e + 96) << 23);  // 2^(e-31) exact
    int isK = (o >= CH);
    int rem = o - (isK ? CH : 0);
    int h = rem >> 6, d = rem & 63;
    signed char* dstb = isK ? K8 : Q8;
    int bn0 = by * 32;
    int bnend = min(bn0 + 32, M_ROWS);
    for (int bn = bn0; bn < bnend; ++bn) {
      int qv = Cq[(size_t)bn * QKV_CH + o];  // wave reads 256B contiguous
      float qf = (float)qv * accs;
      float z = rintf(qf / accs);
      float t8 = rintf((z * mm) * pw);
      t8 = fminf(fmaxf(t8, -128.f), 127.f);
      int b = bn / SEQ, n = bn - b * SEQ;
      dstb[(((size_t)(b * NH + h) * SEQ + n) << 6) + d] = (signed char)t8;
    }
  } else {
    // V: one (bh, 64-n) tile per block, transpose through LDS -> coalesced VT8 writes
    __shared__ __align__(16) signed char VTt[64 * 68];
    int vt = blk - QK_BLKS;                  // [0, 960)
    int bh = vt / 10, n0 = (vt - bh * 10) * 64;
    int b = bh / NH, h = bh - b * NH;
    int od = tid & 63;                       // d within head
    int o = 2 * CH + h * 64 + od;
    float accs = s_x * swq[o];
    float ns = accs / s_qkv;
    int e; float f = frexpf(ns, &e);
    float mm = floorf(f * F2P31 + 0.5f);
    float pw = __int_as_float((e + 96) << 23);
    int nr = tid >> 6;                       // 0..3
    for (int p = 0; p < 16; ++p) {
      int nl = nr * 16 + p;
      int n = n0 + nl;
      signed char v = 0;
      if (n < SEQ) {
        int qv = Cq[(size_t)(b * SEQ + n) * QKV_CH + o];
        float qf = (float)qv * accs;
        float z = rintf(qf / accs);
        float t8 = rintf((z * mm) * pw);
        t8 = fminf(fmaxf(t8, -128.f), 127.f);
        v = (signed char)t8;
      }
      VTt[od * 68 + nl] = v;
    }
    __syncthreads();
    int w16 = tid & 15, dr = tid >> 4;
#pragma unroll
    for (int pp = 0; pp < 4; ++pp) {
      int d = pp * 16 + dr;
      int val = *(const int*)&VTt[d * 68 + w16 * 4];
      *(int*)(VT8 + (size_t)bh * (64 * VT_ROW) + (size_t)d * VT_ROW + n0 + w16 * 4) = val;
    }
  }
}

// ---- attention: 1-D grid 3552, XCD-pinned; integer shiftmax; 16x16x64 MFMA;
// (256,4): proven fit -- waves/EU x VGPR <= 256, sv[10] needs ~64 VGPR. Do not raise.
__global__ __launch_bounds__(256, 4) void k_attn(
    const signed char* __restrict__ Q8, const signed char* __restrict__ K8,
    const signed char* __restrict__ VT8, const unsigned* __restrict__ mxq,
    int* __restrict__ ctxi, unsigned* __restrict__ mxc) {
  __shared__ __align__(16) unsigned char P[16 * P_STRIDE];   // probs [row][m]
  __shared__ int Rmax[4][16];
  __shared__ unsigned long long Rsum[4][16];
  __shared__ float Rav[4];
  int tid = threadIdx.x;
  int t = tid & 63, wid = tid >> 6;
  int lin = blockIdx.x;
  int j = lin >> 3;
  int bh = (lin & 7) * 12 + j / 37;   // 8 XCDs x 12 bh each
  int qt = j % 37;
  int b = bh / NH, h = bh - b * NH;
  int col = t & 15, q4 = t >> 4;
  const signed char* Qb = Q8 + (((size_t)bh * SEQ + qt * 16 + col) << 6);
  i32x4 qa = *(const i32x4*)(Qb + q4 * 16);
  const signed char* Kb = K8 + ((size_t)bh * SEQ << 6);
  int kt0 = wid * 10;
  i32x4 sv[10];
  bool vld[10];
  int mx[4] = {-2147483647 - 1, -2147483647 - 1, -2147483647 - 1, -2147483647 - 1};
#pragma unroll
  for (int u = 0; u < 10; ++u) {
    int kt = kt0 + u;
    int krow = min(kt * 16 + col, SEQ - 1);          // clamp: dead tiles read in-bounds
    const signed char* kr = Kb + ((size_t)krow << 6);
    i32x4 kb = *(const i32x4*)(kr + q4 * 16);
    i32x4 a = {0, 0, 0, 0};
    a = __builtin_amdgcn_mfma_i32_16x16x64_i8(qa, kb, a, 0, 0, 0);
    sv[u] = a;
    bool valid = (kt < 36) | ((kt == 36) & (col < 1));
    vld[u] = valid;
#pragma unroll
    for (int r = 0; r < 4; ++r)
      if (valid) mx[r] = max(mx[r], a[r]);
  }
#pragma unroll
  for (int r = 0; r < 4; ++r) {
    mx[r] = max(mx[r], __shfl_xor(mx[r], 1, 64));
    mx[r] = max(mx[r], __shfl_xor(mx[r], 2, 64));
    mx[r] = max(mx[r], __shfl_xor(mx[r], 4, 64));
    mx[r] = max(mx[r], __shfl_xor(mx[r], 8, 64));
  }
  if (col == 0) {
#pragma unroll
    for (int r = 0; r < 4; ++r) Rmax[wid][q4 * 4 + r] = mx[r];
  }
  __syncthreads();
#pragma unroll
  for (int r = 0; r < 4; ++r) {
    int row = q4 * 4 + r;
    mx[r] = max(max(Rmax[0][row], Rmax[1][row]), max(Rmax[2][row], Rmax[3][row]));
  }
  // ---- integer shiftmax constants (uniform) ----
  float s_qkv = slot_scale(mxq);
  float s_attn = (s_qkv * s_qkv) * 0.125f;
  float x0f = floorf(-1.0f / s_attn);      // identical to ref's x0 (f32 div + floor)
  int x0i = (int)x0f;
  int bi = -x0i;                           // b >= 1, < 16384 in regime
  int nx0i = 15 * x0i;
  int twob = bi << 1;
  unsigned Mq = 0xFFFFFFFFu / (unsigned)bi + 1u;   // ceil(2^32/b) mod 2^32 (0 iff b==1)
  bool bOne = (Mq == 0u);
  unsigned long long su[4] = {0ull, 0ull, 0ull, 0ull};
#pragma unroll
  for (int u = 0; u < 10; ++u) {
#pragma unroll
    for (int r = 0; r < 4; ++r) {
      int d = sv[u][r] - mx[r];                       // <=0 on valid lanes
      int xi = d + (d >> 1) - (d >> 4);               // == d + floor(d/2) - floor(d/16)
      xi = max(xi, nx0i);
      xi = min(xi, 0);                                // guards garbage (invalid lanes only)
      unsigned a = (unsigned)(-xi);                   // in [0, 15b]
      unsigned q = bOne ? a : __umulhi(a, Mq);        // exact floor(a/b) for b<16384
      int rr = (int)(a - q * (unsigned)bi);           // in [0, b)
      unsigned m = (unsigned)(twob - rr);             // m in (b, 2b], m < 2^15
      unsigned ue = (m << 15) >> (q + 1);             // == m<<(14-q) (q<15) / m>>1 (q==15)
      ue = vld[u] ? ue : 0u;
      su[r] += ue;
      sv[u][r] = (int)ue;
    }
  }
#pragma unroll
  for (int r = 0; r < 4; ++r) {
    su[r] += __shfl_xor(su[r], 1, 64);
    su[r] += __shfl_xor(su[r], 2, 64);
    su[r] += __shfl_xor(su[r], 4, 64);
    su[r] += __shfl_xor(su[r], 8, 64);
  }
  if (col == 0) {
#pragma unroll
    for (int r = 0; r < 4; ++r) Rsum[wid][q4 * 4 + r] = su[r];
  }
  __syncthreads();
  float facS[4];
#pragma unroll
  for (int r = 0; r < 4; ++r) {
    int row = q4 * 4 + r;
    unsigned long long dv = ((Rsum[0][row] + Rsum[1][row]) + Rsum[2][row]) + Rsum[3][row];
    float esum = fminf((float)dv, F2P31);   // exact-sum -> f32 RN
    // fac * 2^-24 folded once: exact pow2 scale commutes with f32 rounding of e*fac.
    facS[r] = floorf(F2P31 / esum) * 5.9604644775390625e-08f;
  }
#pragma unroll
  for (int u = 0; u < 10; ++u) {
    int kt = kt0 + u;
#pragma unroll
    for (int r = 0; r < 4; ++r) {
      float e = (float)(unsigned)sv[u][r];     // exact for e < 2^24 (realistic regime)
      int p = (int)floorf(e * facS[r]);        // == floor((e*fac)/2^24), bit-exact
      P[(q4 * 4 + r) * P_STRIDE + kt * 16 + col] = (unsigned char)p;  // covers cols 0..639
    }
  }
  __syncthreads();
  const signed char* Vb = VT8 + (size_t)bh * (64 * VT_ROW);
  i32x4 ac0 = {0, 0, 0, 0}, ac1 = {0, 0, 0, 0};
#pragma unroll
  for (int mc = 0; mc < 10; mc += 2) {
    i32x4 pa0 = *(const i32x4*)&P[col * P_STRIDE + mc * 64 + q4 * 16];
    i32x4 vb0 = *(const i32x4*)(Vb + (size_t)(wid * 16 + col) * VT_ROW + mc * 64 + q4 * 16);
    ac0 = __builtin_amdgcn_mfma_i32_16x16x64_i8(pa0, vb0, ac0, 0, 0, 0);
    i32x4 pa1 = *(const i32x4*)&P[col * P_STRIDE + (mc + 1) * 64 + q4 * 16];
    i32x4 vb1 = *(const i32x4*)(Vb + (size_t)(wid * 16 + col) * VT_ROW + (mc + 1) * 64 + q4 * 16);
    ac1 = __builtin_amdgcn_mfma_i32_16x16x64_i8(pa1, vb1, ac1, 0, 0, 0);
  }
  float pre_s = 0.0078125f * s_qkv;
  float avmax = 0.f;
#pragma unroll
  for (int r = 0; r < 4; ++r) {
    int n = qt * 16 + q4 * 4 + r;
    if (n < SEQ) {
      int cacc = ac0[r] + ac1[r];              // exact integer sum, order-free
      ctxi[((size_t)(b * SEQ + n)) * CH + h * 64 + wid * 16 + col] = cacc;
      avmax = fmaxf(avmax, fabsf((float)cacc * pre_s));
    }
  }
#pragma unroll
  for (int off = 32; off; off >>= 1) avmax = fmaxf(avmax, __shfl_xor(avmax, off, 64));
  if (t == 0) Rav[wid] = avmax;
  __syncthreads();
  if (tid == 0)
    atomicMax(&mxc[(blockIdx.x & (NSLOT - 1)) * SLOT_STRIDE],
              __float_as_uint(fmaxf(fmaxf(Rav[0], Rav[1]), fmaxf(Rav[2], Rav[3]))));
}

// ---------------- requant ctx -> int8 (vectorized x4) ----------------
__global__ void k_ctx_requant(const int* __restrict__ ctxi, const unsigned* __restrict__ mxq,
                              const unsigned* __restrict__ mxc, signed char* __restrict__ C8) {
  float s_qkv = slot_scale(mxq);
  float pre_s = 0.0078125f * s_qkv;
  float s_ctx = slot_scale(mxc);
  float ns = pre_s / s_ctx;
  int e;
  float f = frexpf(ns, &e);
  float mm = floorf(f * F2P31 + 0.5f);
  float pw = exp2f((float)e - 31.0f);
  int total4 = (M_ROWS * CH) / 4;
  int stride = gridDim.x * blockDim.x;
  const int4* src = (const int4*)ctxi;
  int* dst = (int*)C8;
  for (int i = blockIdx.x * blockDim.x + threadIdx.x; i < total4; i += stride) {
    int4 v = src[i];
    int pk = 0;
#pragma unroll
    for (int u = 0; u < 4; ++u) {
      int cv = (u == 0) ? v.x : (u == 1) ? v.y : (u == 2) ? v.z : v.w;
      float cf = (float)cv * pre_s;
      float z = rintf(cf / pre_s);
      float t8 = rintf((z * mm) * pw);
      t8 = fminf(fmaxf(t8, -128.f), 127.f);
      pk |= ((int)(signed char)t8 & 0xff) << (u * 8);
    }
    dst[i] = pk;
  }
}

// ---- GEMM2 (MFMA): 128x64 tiles, 444 blocks (proven round-12 winner), XCD-swizzled ----
#define OUT_GX 12
#define OUT_GY 37
__global__ __launch_bounds__(256) void k_gemm_out(
    const signed char* __restrict__ A, const signed char* __restrict__ Bm,
    const float* __restrict__ swp, const float* __restrict__ bias,
    const unsigned* __restrict__ mxc, float* __restrict__ outp) {
  __shared__ __align__(16) signed char As[8192], Bs[4096];
  int t = threadIdx.x;
  int lane = t & 63, w = t >> 6;
  int c = lane & 15, q = lane >> 4;
  int lr = lane >> 2;
  int ksb = (lane & 3) << 4;
  int sw_id = xcd_swizzle(blockIdx.x, OUT_GX * OUT_GY);
  int bx = sw_id % OUT_GX, by = sw_id / OUT_GX;
  int arow0 = by * 128, bcol0 = bx * 64;
  int arow = arow0 + (w & 1) * 64;
  int bcol = bcol0 + (w >> 1) * 32;
  const signed char* Aw = As + ((w & 1) << 12);
  const signed char* Bw = Bs + ((w >> 1) << 11);   // 32-row half (2KB)
  i32x4 acc[4][2] = {};
  for (int k0 = 0; k0 < CH; k0 += 64) {
#pragma unroll
    for (int u = 0; u < 2; ++u) {
      int row = (w << 5) + (u << 4) + lr;
      __builtin_amdgcn_global_load_lds(
          (const __attribute__((address_space(1))) void*)(A + (size_t)(arow0 + row) * CH + k0 + ksb),
          (__attribute__((address_space(3))) void*)(As + (w << 11) + (u << 10)),
          16, 0, 0);
    }
    {
      int row = (w << 4) + lr;               // 64 B-rows across 4 waves
      __builtin_amdgcn_global_load_lds(
          (const __attribute__((address_space(1))) void*)(Bm + (size_t)(bcol0 + row) * CH + k0 + ksb),
          (__attribute__((address_space(3))) void*)(Bs + (w << 10)),
          16, 0, 0);
    }
    __syncthreads();
    i32x4 af[4], bf[2];
#pragma unroll
    for (int i = 0; i < 4; ++i)
      af[i] = *(const i32x4*)(Aw + (((i << 4) + c) << 6) + (q << 4));
#pragma unroll
    for (int j = 0; j < 2; ++j)
      bf[j] = *(const i32x4*)(Bw + (((j << 4) + c) << 6) + (q << 4));
#pragma unroll
    for (int i = 0; i < 4; ++i)
#pragma unroll
      for (int j = 0; j < 2; ++j)
        acc[i][j] = __builtin_amdgcn_mfma_i32_16x16x64_i8(af[i], bf[j], acc[i][j], 0, 0, 0);
    __syncthreads();
  }
  float s_ctx = slot_scale(mxc);
#pragma unroll
  for (int j = 0; j < 2; ++j) {
    int ccol = bcol + j * 16 + c;
    float outs = s_ctx * swp[ccol];
    int bint = (int)rintf(bias[ccol] / outs);
#pragma unroll
    for (int i = 0; i < 4; ++i)
#pragma unroll
      for (int r = 0; r < 4; ++r) {
        int rr = arow + i * 16 + q * 4 + r;
        if (rr < M_ROWS)
          outp[(size_t)rr * CH + ccol] = (float)(acc[i][j][r] + bint) * outs;
      }
  }
}

extern "C" void kernel_launch(void* const* d_in, const int* in_sizes, int n_in,
                              void* d_out, int out_size, void* d_ws, size_t ws_size,
                              hipStream_t stream) {
  const float* x = (const float*)d_in[0];
  const float* w_qkv = (const float*)d_in[1];
  const float* b_qkv = (const float*)d_in[2];
  const float* w_proj = (const float*)d_in[3];
  const float* b_proj = (const float*)d_in[4];
  float* outp = (float*)d_out;

  // ---- workspace: bump allocator, 4 KB aligned ----
  char* ws = (char*)d_ws;
  size_t off = 0;
  auto alloc = [&](size_t sz) -> char* {
    char* p = ws + off;
    off = (off + sz + 4095) & ~(size_t)4095;
    return p;
  };
  // 3 slot arrays of 64 x 64B: [0]=max|x| [1]=max|qkv_f| [2]=max|ctx_f|
  unsigned* mxx = (unsigned*)alloc(3 * NSLOT * SLOT_STRIDE * 4);
  unsigned* mxq = mxx + NSLOT * SLOT_STRIDE;
  unsigned* mxc = mxq + NSLOT * SLOT_STRIDE;
  float* SWQ = (float*)alloc(QKV_CH * 4);
  float* SWP = (float*)alloc(CH * 4);
  signed char* WQ8 = (signed char*)alloc((size_t)QKV_CH * CH);
  signed char* WP8 = (signed char*)alloc((size_t)CH * CH);
  signed char* X8  = (signed char*)alloc((size_t)(M_ROWS + 128) * CH);
  signed char* Q8  = (signed char*)alloc((size_t)M_ROWS * CH);
  signed char* K8  = (signed char*)alloc((size_t)M_ROWS * CH);
  signed char* VT8 = (signed char*)alloc((size_t)BQ * NH * 64 * VT_ROW);
  signed char* C8  = (signed char*)alloc((size_t)(M_ROWS + 128) * CH);
  int* QKVI = (int*)alloc((size_t)M_ROWS * QKV_CH * 4);
  int* CTXI = (int*)alloc((size_t)M_ROWS * CH * 4);
  (void)ws_size;

  hipMemsetAsync(mxx, 0, 3 * NSLOT * SLOT_STRIDE * 4, stream);
  // 1: fused weight quant + absmax(x)
  k_prep<<<QKV_CH + CH + 1024, 256, 0, stream>>>(x, w_qkv, w_proj, WQ8, SWQ, WP8, SWP, mxx);
  // 2: activation quant
  k_aquant<<<2048, 256, 0, stream>>>(x, NX, mxx, X8);
  // 3: qkv GEMM (128x128 tiles reverted -- proven best; XCD-swizzled)
  k_gemm_qkv<<<QKV_GX * QKV_GY, 256, 0, stream>>>(X8, WQ8, SWQ, b_qkv, mxx, QKVI, mxq);
  // 4: requant (Q/K col-fixed + V LDS-transpose)
  k_qkv_requant<<<QK_BLKS + BQ * NH * 10, 256, 0, stream>>>(QKVI, SWQ, mxx, mxq, Q8, K8, VT8);
  // 5: attention (XCD-pinned 1-D grid, integer shiftmax, 4 blocks/CU proven)
  k_attn<<<37 * BQ * NH, 256, 0, stream>>>(Q8, K8, VT8, mxq, CTXI, mxc);
  // 6: ctx requant
  k_ctx_requant<<<1024, 256, 0, stream>>>(CTXI, mxq, mxc, C8);
  // 7: output GEMM (128x64 tiles, 444 blocks, XCD-swizzled)
  k_gemm_out<<<OUT_GX * OUT_GY, 256, 0, stream>>>(C8, WP8, SWP, b_proj, mxc, outp);
}